// Round 16
// baseline (521.007 us; speedup 1.0000x reference)
//
#include <hip/hip_runtime.h>
#include <hip/hip_bf16.h>
#include <cstdint>
#include <cstddef>

#define BATCH 512
#define SEQL 256
#define DIN 256
#define HID 128
#define OUTD 256
#define G3 384            // 3*H
#define TCH 64            // time chunk
#define NCH 4             // SEQL / TCH
#define NBS 16            // batches per scan block
#define NGRPS (BATCH/NBS) // 32 groups per dir
#define MTOT (BATCH*SEQL) // 131072
#define MCH  (BATCH*TCH)  // 32768 rows per chunk per dir
#define HSPAD 136         // hs row pad (ushorts)
#define NGXT 3072         // gx tiles per chunk: 256 m-tiles x 12 n-tiles

typedef __attribute__((ext_vector_type(8))) short short8v;
typedef __attribute__((ext_vector_type(4))) float float4v;

__device__ __forceinline__ unsigned short f2bf_u(float x) {
  union { float f; uint32_t u; } v; v.f = x;
  uint32_t r = v.u + 0x7FFFu + ((v.u >> 16) & 1u);
  return (unsigned short)(r >> 16);
}
__device__ __forceinline__ float bfu2f(unsigned short u) {
  union { uint32_t u; float f; } v; v.u = ((uint32_t)u) << 16; return v.f;
}
__device__ __forceinline__ float fast_tanh(float x) {
  float e2 = __expf(-2.0f * x);
  return (1.0f - e2) / (1.0f + e2);
}

struct GxB { unsigned short v[3][4]; };   // raw bf16 bits; converted at use

// ---- K0: one-time fp32 -> hi/lo bf16 split for Wmlp, Wih_f, Wih_b ----
__global__ __launch_bounds__(256) void prep_split(
    const float* __restrict__ Wm, unsigned short* __restrict__ mhi, unsigned short* __restrict__ mlo,
    const float* __restrict__ Wf, unsigned short* __restrict__ fhi, unsigned short* __restrict__ flo,
    const float* __restrict__ Wb, unsigned short* __restrict__ bhi, unsigned short* __restrict__ blo)
{
  int gid = blockIdx.x * 256 + threadIdx.x;
  const float* src; unsigned short* hi; unsigned short* lo; int off;
  if (gid < 16384)      { src = Wm; hi = mhi; lo = mlo; off = gid * 4; }
  else if (gid < 40960) { src = Wf; hi = fhi; lo = flo; off = (gid - 16384) * 4; }
  else                  { src = Wb; hi = bhi; lo = blo; off = (gid - 40960) * 4; }
  float4 w4 = *(const float4*)&src[off];
  ushort4 h4, l4;
  h4.x = f2bf_u(w4.x); l4.x = f2bf_u(w4.x - bfu2f(h4.x));
  h4.y = f2bf_u(w4.y); l4.y = f2bf_u(w4.y - bfu2f(h4.y));
  h4.z = f2bf_u(w4.z); l4.z = f2bf_u(w4.z - bfu2f(h4.z));
  h4.w = f2bf_u(w4.w); l4.w = f2bf_u(w4.w - bfu2f(h4.w));
  *(ushort4*)&hi[off] = h4;
  *(ushort4*)&lo[off] = l4;
}

// ======== gx GEMM tile body (256-thread) ========
__device__ __forceinline__ void gx_tile(
    int tid, int m0, int yy,
    const float* __restrict__ X,
    const unsigned short* __restrict__ WhiF, const unsigned short* __restrict__ WloF,
    const unsigned short* __restrict__ WhiB, const unsigned short* __restrict__ WloB,
    const float* __restrict__ bf, const float* __restrict__ bb,
    unsigned short* __restrict__ bufF, unsigned short* __restrict__ bufB, int cF, int cB,
    unsigned short* Abf, unsigned short* Bhi, unsigned short* Blo)
{
  const unsigned short* Whi; const unsigned short* Wlo;
  const float* bias; unsigned short* buf; int c;
  if (yy < 6) { Whi = WhiF; Wlo = WloF; bias = bf; buf = bufF; c = cF; }
  else        { yy -= 6; Whi = WhiB; Wlo = WloB; bias = bb; buf = bufB; c = cB; }
  const int n0 = yy * 64;

  const int l  = tid & 63;
  const int w  = tid >> 6;
  const int fr = l & 15;
  const int fk = (l >> 4) * 8;

  float4v acc[2][4];
#pragma unroll
  for (int a = 0; a < 2; ++a)
#pragma unroll
    for (int nb = 0; nb < 4; ++nb) acc[a][nb] = (float4v)0.0f;

  for (int k0 = 0; k0 < DIN; k0 += 32) {
#pragma unroll
    for (int j = 0; j < 4; ++j) {
      int row = (tid >> 3) + j * 32;
      int kq  = (tid & 7) * 4;
      int r   = m0 + row;
      int b_  = r >> 6, tt = r & 63;
      int xrow = b_ * SEQL + c * TCH + tt;
      float4 x4 = *(const float4*)&X[(size_t)xrow * DIN + k0 + kq];
      ushort4 h4 = {f2bf_u(x4.x), f2bf_u(x4.y), f2bf_u(x4.z), f2bf_u(x4.w)};
      *(ushort4*)&Abf[row * 40 + kq] = h4;
    }
    {
      int half = tid & 1;
      int cc   = tid >> 1;
      int col  = cc >> 1;
      int seg  = (cc & 1) * 16;
      const unsigned short* srcw = (half ? Wlo : Whi) + (size_t)(n0 + col) * DIN + k0 + seg;
      unsigned short* dst = (half ? Blo : Bhi) + col * 40 + seg;
      *(short8v*)dst       = *(const short8v*)srcw;
      *(short8v*)(dst + 8) = *(const short8v*)(srcw + 8);
    }
    __syncthreads();

    short8v ah[2], bh[4], blv[4];
#pragma unroll
    for (int a = 0; a < 2; ++a)
      ah[a] = *(const short8v*)&Abf[(w * 32 + a * 16 + fr) * 40 + fk];
#pragma unroll
    for (int nb = 0; nb < 4; ++nb) {
      bh[nb]  = *(const short8v*)&Bhi[(nb * 16 + fr) * 40 + fk];
      blv[nb] = *(const short8v*)&Blo[(nb * 16 + fr) * 40 + fk];
    }
#pragma unroll
    for (int a = 0; a < 2; ++a)
#pragma unroll
      for (int nb = 0; nb < 4; ++nb) {
        acc[a][nb] = __builtin_amdgcn_mfma_f32_16x16x32_bf16(ah[a], bh[nb],  acc[a][nb], 0, 0, 0);
        acc[a][nb] = __builtin_amdgcn_mfma_f32_16x16x32_bf16(ah[a], blv[nb], acc[a][nb], 0, 0, 0);
      }
    __syncthreads();
  }

#pragma unroll
  for (int a = 0; a < 2; ++a)
#pragma unroll
    for (int nb = 0; nb < 4; ++nb) {
      int gate = n0 + nb * 16 + fr;
      float bv_ = bias[gate];
#pragma unroll
      for (int reg = 0; reg < 4; ++reg) {
        int r = m0 + w * 32 + a * 16 + (l >> 4) * 4 + reg;
        buf[(size_t)r * G3 + gate] = f2bf_u(acc[a][nb][reg] + bv_);
      }
    }
}

// ======== GRU scan: one step (compile-time parity P). Raw gx bits converted here;
// single h conversion via v_cvt_pk_bf16_f32 feeds both LDS and rnn stores. ========
template<int P>
__device__ __forceinline__ void gru_step(
    unsigned short (*hsbuf)[NBS * HSPAD], int col, int rq, int hidx,
    const short8v (&Bh)[3][4], const short8v (&Bl)[3][4], const float (&bias_)[3],
    const GxB& Gc, float (&hold)[4], const int (&len_)[4], int t,
    __hip_bfloat16* (&rp)[4], int drp)
{
  const unsigned short* rd = &hsbuf[P][col * HSPAD + rq * 8];
  short8v ah[4];
#pragma unroll
  for (int ks = 0; ks < 4; ++ks)
    ah[ks] = *(const short8v*)(rd + ks * 32);

  float4v a0 = (float4v){bias_[0] + bfu2f(Gc.v[0][0]), bias_[0] + bfu2f(Gc.v[0][1]),
                         bias_[0] + bfu2f(Gc.v[0][2]), bias_[0] + bfu2f(Gc.v[0][3])};
  float4v a1 = (float4v){bias_[1] + bfu2f(Gc.v[1][0]), bias_[1] + bfu2f(Gc.v[1][1]),
                         bias_[1] + bfu2f(Gc.v[1][2]), bias_[1] + bfu2f(Gc.v[1][3])};
  float4v a2 = (float4v){bias_[2], bias_[2], bias_[2], bias_[2]};
  float4v l0 = (float4v)0.0f, l1 = (float4v)0.0f, l2 = (float4v)0.0f;
#pragma unroll
  for (int ks = 0; ks < 4; ++ks) {
    a0 = __builtin_amdgcn_mfma_f32_16x16x32_bf16(ah[ks], Bh[0][ks], a0, 0, 0, 0);
    l0 = __builtin_amdgcn_mfma_f32_16x16x32_bf16(ah[ks], Bl[0][ks], l0, 0, 0, 0);
    a1 = __builtin_amdgcn_mfma_f32_16x16x32_bf16(ah[ks], Bh[1][ks], a1, 0, 0, 0);
    l1 = __builtin_amdgcn_mfma_f32_16x16x32_bf16(ah[ks], Bl[1][ks], l1, 0, 0, 0);
    a2 = __builtin_amdgcn_mfma_f32_16x16x32_bf16(ah[ks], Bh[2][ks], a2, 0, 0, 0);
    l2 = __builtin_amdgcn_mfma_f32_16x16x32_bf16(ah[ks], Bl[2][ks], l2, 0, 0, 0);
  }
  a0 += l0; a1 += l1; a2 += l2;

  unsigned short* wr = &hsbuf[P ^ 1][rq * 4 * HSPAD + hidx];
  float hv4[4]; bool act4[4];
#pragma unroll
  for (int reg = 0; reg < 4; ++reg) {
    float gr = a0[reg], gz = a1[reg], gn = a2[reg];
    float xn = bfu2f(Gc.v[2][reg]);
    float r = 1.0f / (1.0f + __expf(-gr));
    float z = 1.0f / (1.0f + __expf(-gz));
    float e2 = __expf(-2.0f * (xn + r * gn));
    float cand = (1.0f - e2) / (1.0f + e2);
    float hv = cand + z * (hold[reg] - cand);
    bool act = (t < len_[reg]);
    hv = act ? hv : hold[reg];
    hold[reg] = hv;
    hv4[reg] = hv;
    act4[reg] = act;
  }
  // single conversion: pack 2 f32 -> 2 bf16 per instruction (RNE)
  uint32_t p01, p23;
  asm("v_cvt_pk_bf16_f32 %0, %1, %2" : "=v"(p01) : "v"(hv4[0]), "v"(hv4[1]));
  asm("v_cvt_pk_bf16_f32 %0, %1, %2" : "=v"(p23) : "v"(hv4[2]), "v"(hv4[3]));
  unsigned short b0 = (unsigned short)(p01 & 0xFFFFu);
  unsigned short b1 = (unsigned short)(p01 >> 16);
  unsigned short b2 = (unsigned short)(p23 & 0xFFFFu);
  unsigned short b3 = (unsigned short)(p23 >> 16);
  wr[0 * HSPAD] = b0;
  wr[1 * HSPAD] = b1;
  wr[2 * HSPAD] = b2;
  wr[3 * HSPAD] = b3;
  if (act4[0]) *(unsigned short*)rp[0] = b0;
  if (act4[1]) *(unsigned short*)rp[1] = b1;
  if (act4[2]) *(unsigned short*)rp[2] = b2;
  if (act4[3]) *(unsigned short*)rp[3] = b3;
  rp[0] += drp; rp[1] += drp; rp[2] += drp; rp[3] += drp;

  asm volatile("s_waitcnt lgkmcnt(0)" ::: "memory");
  __builtin_amdgcn_s_barrier();
  __builtin_amdgcn_sched_barrier(0);
}

// ======== GRU scan block body (512-thread) ========
__device__ __forceinline__ void scan_block(
    int sb, int tid,
    const int* __restrict__ seqlens,
    const float* __restrict__ Whh_f, const float* __restrict__ Whh_b,
    const float* __restrict__ bhh_f, const float* __restrict__ bhh_b,
    const unsigned short* __restrict__ bufF, const unsigned short* __restrict__ bufB,
    float* __restrict__ hstate, __hip_bfloat16* __restrict__ rnn, int ci,
    unsigned short (*hsbuf)[NBS * HSPAD])
{
  const int fwd = (sb < NGRPS) ? 1 : 0;
  const int grp = fwd ? sb : (sb - NGRPS);
  const int b0  = grp * NBS;
  const int w   = tid >> 6;
  const int l   = tid & 63;
  const int col = l & 15;
  const int rq  = l >> 4;
  const int hidx = w * 16 + col;
  const float* Whh = fwd ? Whh_f : Whh_b;
  const float* bhh = fwd ? bhh_f : bhh_b;
  const unsigned short* buf = fwd ? bufF : bufB;
  const int c = fwd ? ci : (NCH - 1 - ci);

  __builtin_amdgcn_s_setprio(1);

  short8v Bh[3][4], Bl[3][4];
  float bias_[3];
#pragma unroll
  for (int j = 0; j < 3; ++j) {
    const int g = j * HID + hidx;
    bias_[j] = bhh[g];
#pragma unroll
    for (int ks = 0; ks < 4; ++ks) {
      const float* p = Whh + (size_t)g * HID + ks * 32 + rq * 8;
      float4 x0 = *(const float4*)p;
      float4 x1 = *(const float4*)(p + 4);
      float v[8] = {x0.x, x0.y, x0.z, x0.w, x1.x, x1.y, x1.z, x1.w};
      short8v hi8, lo8;
#pragma unroll
      for (int e = 0; e < 8; ++e) {
        unsigned short h = f2bf_u(v[e]);
        hi8[e] = (short)h;
        lo8[e] = (short)f2bf_u(v[e] - bfu2f(h));
      }
      Bh[j][ks] = hi8; Bl[j][ks] = lo8;
    }
  }

  int len_[4];
#pragma unroll
  for (int reg = 0; reg < 4; ++reg) len_[reg] = seqlens[b0 + rq * 4 + reg];
  int gmax = 0;
  for (int nb = 0; nb < NBS; ++nb) gmax = max(gmax, seqlens[b0 + nb]);

  float* hst = hstate + ((size_t)((fwd ? 0 : 1) * NGRPS + grp)) * (NBS * HID);
  float hold[4];
#pragma unroll
  for (int reg = 0; reg < 4; ++reg) {
    int nb = rq * 4 + reg;
    hold[reg] = (ci == 0) ? 0.0f : hst[nb * HID + hidx];
    hsbuf[0][nb * HSPAD + hidx] = f2bf_u(hold[reg]);
  }
  __syncthreads();

  int nsteps = gmax - c * TCH;
  nsteps = (nsteps > TCH) ? TCH : nsteps;

  const int tcb  = c * TCH;
  const int dofs = fwd ? 0 : HID;

  if (nsteps == TCH) {
    // ---- fast path: 64 steps, unroll-2, RAW gx buffers ----
    const int tt0 = fwd ? 0 : (TCH - 1);
    const int dt  = fwd ? 1 : -1;
    const int dgp = fwd ? G3 : -G3;
    const int drp = fwd ? OUTD : -OUTD;

    const unsigned short* gp[4];
    __hip_bfloat16* rp[4];
#pragma unroll
    for (int reg = 0; reg < 4; ++reg) {
      gp[reg] = buf + (size_t)((b0 + rq * 4 + reg) * TCH + tt0) * G3 + hidx;
      rp[reg] = rnn + (size_t)((b0 + rq * 4 + reg) * SEQL + tcb + tt0) * OUTD + dofs + hidx;
    }

    GxB GA, GB;
    auto LOADGX = [&](GxB& G) {
#pragma unroll
      for (int reg = 0; reg < 4; ++reg) {
        G.v[0][reg] = gp[reg][0];
        G.v[1][reg] = gp[reg][HID];
        G.v[2][reg] = gp[reg][2 * HID];
        gp[reg] += dgp;
      }
    };
    LOADGX(GA);
    LOADGX(GB);

    int t = tcb + tt0;
#pragma unroll 1
    for (int it = 0; it < TCH / 2; ++it) {
      gru_step<0>(hsbuf, col, rq, hidx, Bh, Bl, bias_, GA, hold, len_, t, rp, drp);
      t += dt;
      LOADGX(GA);
      gru_step<1>(hsbuf, col, rq, hidx, Bh, Bl, bias_, GB, hold, len_, t, rp, drp);
      t += dt;
      LOADGX(GB);
    }
  } else if (nsteps > 0) {
    // ---- slow path: partial chunk ----
    float gxc[3][4], gxn[3][4];
    {
      int tt0 = fwd ? 0 : (nsteps - 1);
#pragma unroll
      for (int j = 0; j < 3; ++j)
#pragma unroll
        for (int reg = 0; reg < 4; ++reg)
          gxc[j][reg] = bfu2f(buf[(size_t)((b0 + rq * 4 + reg) * TCH + tt0) * G3 + j * HID + hidx]);
    }

    int cur = 0;
    for (int ss = 0; ss < nsteps; ++ss) {
      const int tt = fwd ? ss : (nsteps - 1 - ss);
      const int t  = tcb + tt;

      short8v ah[4];
#pragma unroll
      for (int ks = 0; ks < 4; ++ks)
        ah[ks] = *(const short8v*)&hsbuf[cur][col * HSPAD + ks * 32 + rq * 8];

      {
        int ssn = (ss + 1 < nsteps) ? (ss + 1) : ss;
        int ttn = fwd ? ssn : (nsteps - 1 - ssn);
#pragma unroll
        for (int j = 0; j < 3; ++j)
#pragma unroll
          for (int reg = 0; reg < 4; ++reg)
            gxn[j][reg] = bfu2f(buf[(size_t)((b0 + rq * 4 + reg) * TCH + ttn) * G3 + j * HID + hidx]);
      }

      float4v acc[3], accl[3];
#pragma unroll
      for (int j = 0; j < 3; ++j) {
        acc[j]  = (float4v){bias_[j], bias_[j], bias_[j], bias_[j]};
        accl[j] = (float4v)0.0f;
      }
#pragma unroll
      for (int ks = 0; ks < 4; ++ks) {
#pragma unroll
        for (int j = 0; j < 3; ++j) {
          acc[j]  = __builtin_amdgcn_mfma_f32_16x16x32_bf16(ah[ks], Bh[j][ks], acc[j],  0, 0, 0);
          accl[j] = __builtin_amdgcn_mfma_f32_16x16x32_bf16(ah[ks], Bl[j][ks], accl[j], 0, 0, 0);
        }
      }
#pragma unroll
      for (int j = 0; j < 3; ++j) acc[j] += accl[j];

#pragma unroll
      for (int reg = 0; reg < 4; ++reg) {
        int nb = rq * 4 + reg;
        float gr = acc[0][reg] + gxc[0][reg];
        float gz = acc[1][reg] + gxc[1][reg];
        float gn = acc[2][reg];
        float xn = gxc[2][reg];
        float r = 1.0f / (1.0f + __expf(-gr));
        float z = 1.0f / (1.0f + __expf(-gz));
        float e2 = __expf(-2.0f * (xn + r * gn));
        float cand = (1.0f - e2) / (1.0f + e2);
        float hv = (1.0f - z) * cand + z * hold[reg];
        bool act = (t < len_[reg]);
        hv = act ? hv : hold[reg];
        hold[reg] = hv;
        hsbuf[cur ^ 1][nb * HSPAD + hidx] = f2bf_u(hv);
        if (act)
          rnn[(size_t)((b0 + nb) * SEQL + t) * OUTD + dofs + hidx] = __float2bfloat16(hv);
      }
      asm volatile("s_waitcnt lgkmcnt(0)" ::: "memory");
      __builtin_amdgcn_s_barrier();
      __builtin_amdgcn_sched_barrier(0);
      cur ^= 1;

#pragma unroll
      for (int j = 0; j < 3; ++j)
#pragma unroll
        for (int reg = 0; reg < 4; ++reg) gxc[j][reg] = gxn[j][reg];
    }
  }

  __builtin_amdgcn_s_setprio(0);

#pragma unroll
  for (int reg = 0; reg < 4; ++reg)
    hst[(rq * 4 + reg) * HID + hidx] = hold[reg];
}

// ======== mlp 64-row tile body (256-thread) ========
__device__ __forceinline__ void mlp64_tile(
    int tid, int m0, int nh,
    const __hip_bfloat16* __restrict__ rnn,
    const unsigned short* __restrict__ Whi, const unsigned short* __restrict__ Wlo,
    const float* __restrict__ bmlp, const float* __restrict__ ctx,
    float* __restrict__ scoresH,
    unsigned short* Abf, unsigned short* BhiS, unsigned short* BloS)
{
  const int l  = tid & 63;
  const int w  = tid >> 6;
  const int fr = l & 15;
  const int fk = (l >> 4) * 8;

  float bl_[8], cl_[8];
#pragma unroll
  for (int nt = 0; nt < 8; ++nt) {
    bl_[nt] = bmlp[nh * 128 + nt * 16 + fr];
    cl_[nt] = ctx[nh * 128 + nt * 16 + fr];
  }

  float4v acc[8];
#pragma unroll
  for (int nt = 0; nt < 8; ++nt) acc[nt] = (float4v)0.0f;

  for (int k0 = 0; k0 < OUTD; k0 += 32) {
    {
      int row = tid >> 2;
      int kq  = (tid & 3) * 8;
      *(short8v*)&Abf[row * 40 + kq] =
          *(const short8v*)((const short*)rnn + (size_t)(m0 + row) * OUTD + k0 + kq);
    }
#pragma unroll
    for (int j = 0; j < 2; ++j) {
      int cid  = tid * 2 + j;
      int half = cid >> 8;
      int cc   = cid & 255;
      int colx = cc >> 1;
      int seg  = (cc & 1) * 16;
      const unsigned short* srcw = (half ? Wlo : Whi) + (size_t)(nh * 128 + colx) * OUTD + k0 + seg;
      unsigned short* dst = (half ? BloS : BhiS) + colx * 40 + seg;
      *(short8v*)dst       = *(const short8v*)srcw;
      *(short8v*)(dst + 8) = *(const short8v*)(srcw + 8);
    }
    __syncthreads();

    short8v a = *(const short8v*)&Abf[(w * 16 + fr) * 40 + fk];
#pragma unroll
    for (int nt = 0; nt < 8; ++nt) {
      short8v bh = *(const short8v*)&BhiS[(nt * 16 + fr) * 40 + fk];
      short8v bv = *(const short8v*)&BloS[(nt * 16 + fr) * 40 + fk];
      acc[nt] = __builtin_amdgcn_mfma_f32_16x16x32_bf16(a, bh, acc[nt], 0, 0, 0);
      acc[nt] = __builtin_amdgcn_mfma_f32_16x16x32_bf16(a, bv, acc[nt], 0, 0, 0);
    }
    __syncthreads();
  }

  float p[4] = {0.f, 0.f, 0.f, 0.f};
#pragma unroll
  for (int nt = 0; nt < 8; ++nt) {
    float bv_ = bl_[nt], cv = cl_[nt];
#pragma unroll
    for (int reg = 0; reg < 4; ++reg)
      p[reg] += fast_tanh(acc[nt][reg] + bv_) * cv;
  }
#pragma unroll
  for (int off = 1; off < 16; off <<= 1)
#pragma unroll
    for (int reg = 0; reg < 4; ++reg) p[reg] += __shfl_xor(p[reg], off, 64);
  if (fr == 0) {
#pragma unroll
    for (int reg = 0; reg < 4; ++reg)
      scoresH[(size_t)nh * MTOT + m0 + w * 16 + (l >> 4) * 4 + reg] = p[reg];
  }
}

// ---- standalone gx kernel (prologue + fallback) ----
__global__ __launch_bounds__(256) void gx_kernel(
    const float* __restrict__ X,
    const unsigned short* __restrict__ WhiF, const unsigned short* __restrict__ WloF,
    const unsigned short* __restrict__ WhiB, const unsigned short* __restrict__ WloB,
    const float* __restrict__ bf, const float* __restrict__ bb,
    unsigned short* __restrict__ bufF, unsigned short* __restrict__ bufB, int cF, int cB)
{
  __shared__ unsigned short Abf[128 * 40];
  __shared__ unsigned short Bhi[64 * 40];
  __shared__ unsigned short Blo[64 * 40];
  gx_tile(threadIdx.x, blockIdx.x * 128, blockIdx.y, X, WhiF, WloF, WhiB, WloB,
          bf, bb, bufF, bufB, cF, cB, Abf, Bhi, Blo);
}

// ---- standalone scan kernel (fallback) ----
__global__ __launch_bounds__(512, 2) void scan_kernel(
    const int* __restrict__ seqlens,
    const float* __restrict__ Whh_f, const float* __restrict__ Whh_b,
    const float* __restrict__ bhh_f, const float* __restrict__ bhh_b,
    const unsigned short* __restrict__ bufF, const unsigned short* __restrict__ bufB,
    float* __restrict__ hstate, __hip_bfloat16* __restrict__ rnn, int ci)
{
  __shared__ unsigned short hsbuf[2][NBS * HSPAD];
  scan_block(blockIdx.x, threadIdx.x, seqlens, Whh_f, Whh_b, bhh_f, bhh_b,
             bufF, bufB, hstate, rnn, ci, hsbuf);
}

// ---- fused kernel: blocks 0..63 scan chunk ci; blocks 64.. gx chunk ci+1.
// LDS padded >80KB so only ONE block fits per CU: scan blocks get exclusive CUs
// (no gx issue contention); gx spreads over the other 192 CUs and stays hidden. ----
__global__ __launch_bounds__(512, 1) void fused_kernel(
    const int* __restrict__ seqlens,
    const float* __restrict__ Whh_f, const float* __restrict__ Whh_b,
    const float* __restrict__ bhh_f, const float* __restrict__ bhh_b,
    const float* __restrict__ X,
    const unsigned short* __restrict__ WhiF, const unsigned short* __restrict__ WloF,
    const unsigned short* __restrict__ WhiB, const unsigned short* __restrict__ WloB,
    const float* __restrict__ bf, const float* __restrict__ bb,
    const unsigned short* __restrict__ rdF, const unsigned short* __restrict__ rdB,
    unsigned short* __restrict__ wrF, unsigned short* __restrict__ wrB,
    float* __restrict__ hstate, __hip_bfloat16* __restrict__ rnn, int ci)
{
  __shared__ unsigned short hsbuf[2][NBS * HSPAD];
  __shared__ unsigned short AbfS[2][128 * 40];
  __shared__ unsigned short BhiS[2][64 * 40];
  __shared__ unsigned short BloS[2][64 * 40];
  __shared__ int lds_pad[10240];   // 40KB: forces 1 block/CU (total ~90.6KB > 160/2)
  if (seqlens[0] == 0x7fffffff) ((volatile int*)lds_pad)[0] = threadIdx.x;  // keep alloc

  if (blockIdx.x < 2 * NGRPS) {
    scan_block(blockIdx.x, threadIdx.x, seqlens, Whh_f, Whh_b, bhh_f, bhh_b,
               rdF, rdB, hstate, rnn, ci, hsbuf);
  } else {
    const int gb   = blockIdx.x - 2 * NGRPS;
    const int half = threadIdx.x >> 8;
    const int htid = threadIdx.x & 255;
    const int t0   = gb * 2 + half;
    const int m0   = (t0 & 255) * 128;
    const int yy   = t0 >> 8;
    gx_tile(htid, m0, yy, X, WhiF, WloF, WhiB, WloB, bf, bb,
            wrF, wrB, ci + 1, NCH - 2 - ci, AbfS[half], BhiS[half], BloS[half]);
  }
}

// ---- fused final: blocks 0..63 scan chunk NCH-1; blocks 64.. mlp tiles for t in [64,192) ----
union ShFinal {
  unsigned short hs[2][NBS * HSPAD];
  struct { unsigned short A[2][64 * 40]; unsigned short Bh[2][128 * 40]; unsigned short Bl[2][128 * 40]; } m;
};
__global__ __launch_bounds__(512, 1) void fused_final(
    const int* __restrict__ seqlens,
    const float* __restrict__ Whh_f, const float* __restrict__ Whh_b,
    const float* __restrict__ bhh_f, const float* __restrict__ bhh_b,
    const unsigned short* __restrict__ rdF, const unsigned short* __restrict__ rdB,
    float* __restrict__ hstate, __hip_bfloat16* __restrict__ rnn,
    const unsigned short* __restrict__ mhi, const unsigned short* __restrict__ mlo,
    const float* __restrict__ bmlp, const float* __restrict__ ctx,
    float* __restrict__ scoresH)
{
  __shared__ ShFinal sh;
  __shared__ int lds_pad[10240];   // 40KB: forces 1 block/CU
  if (seqlens[0] == 0x7fffffff) ((volatile int*)lds_pad)[0] = threadIdx.x;

  if (blockIdx.x < 2 * NGRPS) {
    scan_block(blockIdx.x, threadIdx.x, seqlens, Whh_f, Whh_b, bhh_f, bhh_b,
               rdF, rdB, hstate, rnn, NCH - 1, sh.hs);
  } else {
    const int gb   = blockIdx.x - 2 * NGRPS;
    const int half = threadIdx.x >> 8;
    const int htid = threadIdx.x & 255;
    const int body = gb * 2 + half;
    const int nh   = body & 1;
    const int tile = body >> 1;
    const int b    = tile >> 1;
    const int t0   = 64 + (tile & 1) * 64;
    const int m0   = b * SEQL + t0;
    mlp64_tile(htid, m0, nh, rnn, mhi, mlo, bmlp, ctx, scoresH,
               sh.m.A[half], sh.m.Bh[half], sh.m.Bl[half]);
  }
}

// ---- tail kernel: per-batch missing scores + masked softmax + pool ----
__global__ __launch_bounds__(256) void tail_kernel(
    const int* __restrict__ seqlens,
    const __hip_bfloat16* __restrict__ rnn,
    const unsigned short* __restrict__ Whi, const unsigned short* __restrict__ Wlo,
    const float* __restrict__ bmlp, const float* __restrict__ ctx,
    const float* __restrict__ scoresH,
    float* __restrict__ out)
{
  __shared__ unsigned short Abf[128 * 40];
  __shared__ unsigned short BhiS[128 * 40];
  __shared__ unsigned short BloS[128 * 40];
  __shared__ float sm[SEQL];
  __shared__ float red[8];

  const int tid = threadIdx.x;
  const int b   = blockIdx.x;
  const int len = seqlens[b];
  const int l   = tid & 63;
  const int w   = tid >> 6;
  const int fr  = l & 15;
  const int fk  = (l >> 4) * 8;

  float pfull[2][4] = {{0.f, 0.f, 0.f, 0.f}, {0.f, 0.f, 0.f, 0.f}};

  for (int nh = 0; nh < 2; ++nh) {
    float bl_[8], cl_[8];
#pragma unroll
    for (int nt = 0; nt < 8; ++nt) {
      bl_[nt] = bmlp[nh * 128 + nt * 16 + fr];
      cl_[nt] = ctx[nh * 128 + nt * 16 + fr];
    }

    float4v acc[2][8];
#pragma unroll
    for (int a = 0; a < 2; ++a)
#pragma unroll
      for (int nt = 0; nt < 8; ++nt) acc[a][nt] = (float4v)0.0f;

    for (int k0 = 0; k0 < OUTD; k0 += 32) {
      {
        int row = tid >> 1;
        int kq  = (tid & 1) * 16;
        int t   = (row < 64) ? row : (row + 128);
        const short* src = (const short*)rnn + (size_t)(b * SEQL + t) * OUTD + k0 + kq;
        *(short8v*)&Abf[row * 40 + kq]     = *(const short8v*)src;
        *(short8v*)&Abf[row * 40 + kq + 8] = *(const short8v*)(src + 8);
      }
#pragma unroll
      for (int j = 0; j < 2; ++j) {
        int cid  = tid * 2 + j;
        int half = cid >> 8;
        int cc   = cid & 255;
        int colx = cc >> 1;
        int seg  = (cc & 1) * 16;
        const unsigned short* srcw = (half ? Wlo : Whi) + (size_t)(nh * 128 + colx) * OUTD + k0 + seg;
        unsigned short* dst = (half ? BloS : BhiS) + colx * 40 + seg;
        *(short8v*)dst       = *(const short8v*)srcw;
        *(short8v*)(dst + 8) = *(const short8v*)(srcw + 8);
      }
      __syncthreads();

      short8v ah0 = *(const short8v*)&Abf[(w * 32 + fr) * 40 + fk];
      short8v ah1 = *(const short8v*)&Abf[(w * 32 + 16 + fr) * 40 + fk];
#pragma unroll
      for (int nt = 0; nt < 8; ++nt) {
        short8v bh = *(const short8v*)&BhiS[(nt * 16 + fr) * 40 + fk];
        short8v bv = *(const short8v*)&BloS[(nt * 16 + fr) * 40 + fk];
        acc[0][nt] = __builtin_amdgcn_mfma_f32_16x16x32_bf16(ah0, bh, acc[0][nt], 0, 0, 0);
        acc[0][nt] = __builtin_amdgcn_mfma_f32_16x16x32_bf16(ah0, bv, acc[0][nt], 0, 0, 0);
        acc[1][nt] = __builtin_amdgcn_mfma_f32_16x16x32_bf16(ah1, bh, acc[1][nt], 0, 0, 0);
        acc[1][nt] = __builtin_amdgcn_mfma_f32_16x16x32_bf16(ah1, bv, acc[1][nt], 0, 0, 0);
      }
      __syncthreads();
    }

#pragma unroll
    for (int a = 0; a < 2; ++a)
#pragma unroll
      for (int nt = 0; nt < 8; ++nt) {
        float bv_ = bl_[nt], cv = cl_[nt];
#pragma unroll
        for (int reg = 0; reg < 4; ++reg)
          pfull[a][reg] += fast_tanh(acc[a][nt][reg] + bv_) * cv;
      }
  }

#pragma unroll
  for (int a = 0; a < 2; ++a) {
#pragma unroll
    for (int off = 1; off < 16; off <<= 1)
#pragma unroll
      for (int reg = 0; reg < 4; ++reg) pfull[a][reg] += __shfl_xor(pfull[a][reg], off, 64);
  }
  if (fr == 0) {
#pragma unroll
    for (int a = 0; a < 2; ++a)
#pragma unroll
      for (int reg = 0; reg < 4; ++reg) {
        int rr = w * 32 + a * 16 + (l >> 4) * 4 + reg;
        int t  = (rr < 64) ? rr : (rr + 128);
        sm[t] = pfull[a][reg];
      }
  }
  if (tid < 128)
    sm[64 + tid] = scoresH[b * SEQL + 64 + tid] + scoresH[(size_t)MTOT + b * SEQL + 64 + tid];
  __syncthreads();

  float s = (tid < len) ? sm[tid] : -3.4e38f;
  float wm = s;
#pragma unroll
  for (int off = 32; off > 0; off >>= 1) wm = fmaxf(wm, __shfl_xor(wm, off, 64));
  if ((tid & 63) == 0) red[tid >> 6] = wm;
  __syncthreads();
  float bm = fmaxf(fmaxf(red[0], red[1]), fmaxf(red[2], red[3]));

  float e = (tid < len) ? __expf(s - bm) : 0.0f;
  __syncthreads();
  sm[tid] = e;
  float sum = e;
#pragma unroll
  for (int off = 32; off > 0; off >>= 1) sum += __shfl_xor(sum, off, 64);
  if ((tid & 63) == 0) red[4 + (tid >> 6)] = sum;
  __syncthreads();
  float inv = 1.0f / (red[4] + red[5] + red[6] + red[7]);

  float acc = 0.0f;
  for (int l2 = 0; l2 < len; ++l2)
    acc += sm[l2] * __bfloat162float(rnn[(size_t)(b * SEQL + l2) * OUTD + tid]);
  out[b * OUTD + tid] = acc * inv;
}

// ---- K3 full (fallback path) ----
__global__ __launch_bounds__(256) void mlp_score(
    const __hip_bfloat16* __restrict__ rnn,
    const unsigned short* __restrict__ Whi, const unsigned short* __restrict__ Wlo,
    const float* __restrict__ bmlp, const float* __restrict__ ctx,
    float* __restrict__ scoresH)
{
  __shared__ unsigned short Abf[128 * 40];
  __shared__ unsigned short BhiS[128 * 40];
  __shared__ unsigned short BloS[128 * 40];

  const int tid = threadIdx.x;
  const int m0  = blockIdx.x * 128;
  const int nh  = blockIdx.y;
  const int l   = tid & 63;
  const int w   = tid >> 6;
  const int fr  = l & 15;
  const int fk  = (l >> 4) * 8;

  float bl_[8], cl_[8];
#pragma unroll
  for (int nt = 0; nt < 8; ++nt) {
    bl_[nt] = bmlp[nh * 128 + nt * 16 + fr];
    cl_[nt] = ctx[nh * 128 + nt * 16 + fr];
  }

  float4v acc[2][8];
#pragma unroll
  for (int a = 0; a < 2; ++a)
#pragma unroll
    for (int nt = 0; nt < 8; ++nt) acc[a][nt] = (float4v)0.0f;

  for (int k0 = 0; k0 < OUTD; k0 += 32) {
    {
      int row = tid >> 1;
      int kq  = (tid & 1) * 16;
      const short* src = (const short*)rnn + (size_t)(m0 + row) * OUTD + k0 + kq;
      *(short8v*)&Abf[row * 40 + kq]     = *(const short8v*)src;
      *(short8v*)&Abf[row * 40 + kq + 8] = *(const short8v*)(src + 8);
    }
#pragma unroll
    for (int j = 0; j < 2; ++j) {
      int cid  = tid * 2 + j;
      int half = cid >> 8;
      int cc   = cid & 255;
      int colx = cc >> 1;
      int seg  = (cc & 1) * 16;
      const unsigned short* srcw = (half ? Wlo : Whi) + (size_t)(nh * 128 + colx) * OUTD + k0 + seg;
      unsigned short* dst = (half ? BloS : BhiS) + colx * 40 + seg;
      *(short8v*)dst       = *(const short8v*)srcw;
      *(short8v*)(dst + 8) = *(const short8v*)(srcw + 8);
    }
    __syncthreads();

    short8v ah0 = *(const short8v*)&Abf[(w * 32 + fr) * 40 + fk];
    short8v ah1 = *(const short8v*)&Abf[(w * 32 + 16 + fr) * 40 + fk];
#pragma unroll
    for (int nt = 0; nt < 8; ++nt) {
      short8v bh = *(const short8v*)&BhiS[(nt * 16 + fr) * 40 + fk];
      short8v bv = *(const short8v*)&BloS[(nt * 16 + fr) * 40 + fk];
      acc[0][nt] = __builtin_amdgcn_mfma_f32_16x16x32_bf16(ah0, bh, acc[0][nt], 0, 0, 0);
      acc[0][nt] = __builtin_amdgcn_mfma_f32_16x16x32_bf16(ah0, bv, acc[0][nt], 0, 0, 0);
      acc[1][nt] = __builtin_amdgcn_mfma_f32_16x16x32_bf16(ah1, bh, acc[1][nt], 0, 0, 0);
      acc[1][nt] = __builtin_amdgcn_mfma_f32_16x16x32_bf16(ah1, bv, acc[1][nt], 0, 0, 0);
    }
    __syncthreads();
  }

#pragma unroll
  for (int a = 0; a < 2; ++a) {
    float p[4] = {0.f, 0.f, 0.f, 0.f};
#pragma unroll
    for (int nt = 0; nt < 8; ++nt) {
      float bv_ = bl_[nt], cv = cl_[nt];
#pragma unroll
      for (int reg = 0; reg < 4; ++reg)
        p[reg] += fast_tanh(acc[a][nt][reg] + bv_) * cv;
    }
#pragma unroll
    for (int off = 1; off < 16; off <<= 1)
#pragma unroll
      for (int reg = 0; reg < 4; ++reg) p[reg] += __shfl_xor(p[reg], off, 64);
    if (fr == 0) {
#pragma unroll
      for (int reg = 0; reg < 4; ++reg)
        scoresH[(size_t)nh * MTOT + m0 + w * 32 + a * 16 + (l >> 4) * 4 + reg] = p[reg];
    }
  }
}

// ---- K4: masked softmax over l + weighted pool (fallback path) ----
__global__ __launch_bounds__(256) void softmax_pool(
    const int* __restrict__ seqlens,
    const float* __restrict__ scoresH,
    const __hip_bfloat16* __restrict__ rnn,
    float* __restrict__ out)
{
  const int b = blockIdx.x;
  const int len = seqlens[b];
  const int tid = threadIdx.x;
  __shared__ float sm[SEQL];
  __shared__ float red[8];

  float s = (tid < len)
      ? (scoresH[b * SEQL + tid] + scoresH[(size_t)MTOT + b * SEQL + tid])
      : -3.4e38f;
  float wm = s;
#pragma unroll
  for (int off = 32; off > 0; off >>= 1) wm = fmaxf(wm, __shfl_xor(wm, off, 64));
  if ((tid & 63) == 0) red[tid >> 6] = wm;
  __syncthreads();
  float bm = fmaxf(fmaxf(red[0], red[1]), fmaxf(red[2], red[3]));

  float e = (tid < len) ? expf(s - bm) : 0.0f;
  sm[tid] = e;
  float sum = e;
#pragma unroll
  for (int off = 32; off > 0; off >>= 1) sum += __shfl_xor(sum, off, 64);
  if ((tid & 63) == 0) red[4 + (tid >> 6)] = sum;
  __syncthreads();
  float inv = 1.0f / (red[4] + red[5] + red[6] + red[7]);

  float acc = 0.0f;
  for (int l = 0; l < len; ++l)
    acc += sm[l] * __bfloat162float(rnn[(size_t)(b * SEQL + l) * OUTD + tid]);
  out[b * OUTD + tid] = acc * inv;
}

extern "C" void kernel_launch(void* const* d_in, const int* in_sizes, int n_in,
                              void* d_out, int out_size, void* d_ws, size_t ws_size,
                              hipStream_t stream) {
  const float* seq    = (const float*)d_in[0];
  const int*   lens   = (const int*)d_in[1];
  const float* Wih_f  = (const float*)d_in[2];
  const float* Whh_f  = (const float*)d_in[3];
  const float* bih_f  = (const float*)d_in[4];
  const float* bhh_f  = (const float*)d_in[5];
  const float* Wih_b  = (const float*)d_in[6];
  const float* Whh_b  = (const float*)d_in[7];
  const float* bih_b  = (const float*)d_in[8];
  const float* bhh_b  = (const float*)d_in[9];
  const float* Wmlp   = (const float*)d_in[10];
  const float* bmlp   = (const float*)d_in[11];
  const float* ctx    = (const float*)d_in[12];
  float* out = (float*)d_out;

  const size_t BUFSZ = (size_t)MCH * G3;
  const size_t needOverlap =
      4 * BUFSZ * 2 + (size_t)MTOT * OUTD * 2 + 2 * (size_t)MTOT * 4 +
      2 * BATCH * HID * 4 + 2 * (size_t)OUTD * OUTD * 2 + 4 * (size_t)G3 * DIN * 2;
  const bool overlap = (ws_size >= needOverlap);

  unsigned short* buf0F = (unsigned short*)d_ws;
  unsigned short* buf0B = buf0F + BUFSZ;
  unsigned short* buf1F = overlap ? (buf0B + BUFSZ) : buf0F;
  unsigned short* buf1B = overlap ? (buf1F + BUFSZ) : buf0B;
  unsigned short* tail  = overlap ? (buf1B + BUFSZ) : (buf0B + BUFSZ);

  __hip_bfloat16* rnn  = (__hip_bfloat16*)tail;
  float* scoresH = (float*)((unsigned short*)rnn + (size_t)MTOT * OUTD);
  float* hstate  = scoresH + 2 * (size_t)MTOT;
  unsigned short* mhi = (unsigned short*)(hstate + 2 * BATCH * HID);
  unsigned short* mlo = mhi + OUTD * OUTD;
  unsigned short* fhi = mlo + OUTD * OUTD;
  unsigned short* flo = fhi + G3 * DIN;
  unsigned short* bhi2 = flo + G3 * DIN;
  unsigned short* blo2 = bhi2 + G3 * DIN;

  prep_split<<<dim3(256), 256, 0, stream>>>(Wmlp, mhi, mlo, Wih_f, fhi, flo, Wih_b, bhi2, blo2);

  if (overlap) {
    unsigned short* bp[2][2] = {{buf0F, buf0B}, {buf1F, buf1B}};
    gx_kernel<<<dim3(256, 12), 256, 0, stream>>>(seq, fhi, flo, bhi2, blo2, bih_f, bih_b,
                                                 bp[0][0], bp[0][1], 0, NCH - 1);
    for (int k = 0; k < NCH - 1; ++k) {
      fused_kernel<<<dim3(2 * NGRPS + NGXT / 2), 512, 0, stream>>>(
          lens, Whh_f, Whh_b, bhh_f, bhh_b,
          seq, fhi, flo, bhi2, blo2, bih_f, bih_b,
          bp[k & 1][0], bp[k & 1][1], bp[(k + 1) & 1][0], bp[(k + 1) & 1][1],
          hstate, rnn, k);
    }
    fused_final<<<dim3(2 * NGRPS + 1024), 512, 0, stream>>>(
        lens, Whh_f, Whh_b, bhh_f, bhh_b,
        bp[(NCH - 1) & 1][0], bp[(NCH - 1) & 1][1], hstate, rnn,
        mhi, mlo, bmlp, ctx, scoresH);
    tail_kernel<<<dim3(BATCH), 256, 0, stream>>>(lens, rnn, mhi, mlo, bmlp, ctx, scoresH, out);
  } else {
    for (int ci = 0; ci < NCH; ++ci) {
      gx_kernel<<<dim3(256, 12), 256, 0, stream>>>(seq, fhi, flo, bhi2, blo2, bih_f, bih_b,
                                                   buf0F, buf0B, ci, NCH - 1 - ci);
      scan_kernel<<<dim3(2 * NGRPS), 512, 0, stream>>>(
          lens, Whh_f, Whh_b, bhh_f, bhh_b, buf0F, buf0B, hstate, rnn, ci);
    }
    mlp_score<<<dim3(MTOT / 128, 2), 256, 0, stream>>>(rnn, mhi, mlo, bmlp, ctx, scoresH);
    softmax_pool<<<dim3(BATCH), 256, 0, stream>>>(lens, scoresH, rnn, out);
  }
}

// Round 17
// 510.593 us; speedup vs baseline: 1.0204x; 1.0204x over previous
//
#include <hip/hip_runtime.h>
#include <hip/hip_bf16.h>
#include <cstdint>
#include <cstddef>

#define BATCH 512
#define SEQL 256
#define DIN 256
#define HID 128
#define OUTD 256
#define G3 384            // 3*H
#define TCH 64            // time chunk
#define NCH 4             // SEQL / TCH
#define NBS 16            // batches per scan block
#define NGRPS (BATCH/NBS) // 32 groups per dir
#define MTOT (BATCH*SEQL) // 131072
#define MCH  (BATCH*TCH)  // 32768 rows per chunk per dir
#define HSPAD 136         // hs row pad (ushorts)
#define NGXT 3072         // gx tiles per chunk: 256 m-tiles x 12 n-tiles

typedef __attribute__((ext_vector_type(8))) short short8v;
typedef __attribute__((ext_vector_type(4))) float float4v;

__device__ __forceinline__ unsigned short f2bf_u(float x) {
  union { float f; uint32_t u; } v; v.f = x;
  uint32_t r = v.u + 0x7FFFu + ((v.u >> 16) & 1u);
  return (unsigned short)(r >> 16);
}
__device__ __forceinline__ float bfu2f(unsigned short u) {
  union { uint32_t u; float f; } v; v.u = ((uint32_t)u) << 16; return v.f;
}
__device__ __forceinline__ float fast_tanh(float x) {
  float e2 = __expf(-2.0f * x);
  return (1.0f - e2) / (1.0f + e2);
}

struct GxB { unsigned short v[3][4]; };   // raw bf16 bits; converted at use

// ---- K0: one-time fp32 -> hi/lo bf16 split for Wmlp, Wih_f, Wih_b ----
__global__ __launch_bounds__(256) void prep_split(
    const float* __restrict__ Wm, unsigned short* __restrict__ mhi, unsigned short* __restrict__ mlo,
    const float* __restrict__ Wf, unsigned short* __restrict__ fhi, unsigned short* __restrict__ flo,
    const float* __restrict__ Wb, unsigned short* __restrict__ bhi, unsigned short* __restrict__ blo)
{
  int gid = blockIdx.x * 256 + threadIdx.x;
  const float* src; unsigned short* hi; unsigned short* lo; int off;
  if (gid < 16384)      { src = Wm; hi = mhi; lo = mlo; off = gid * 4; }
  else if (gid < 40960) { src = Wf; hi = fhi; lo = flo; off = (gid - 16384) * 4; }
  else                  { src = Wb; hi = bhi; lo = blo; off = (gid - 40960) * 4; }
  float4 w4 = *(const float4*)&src[off];
  ushort4 h4, l4;
  h4.x = f2bf_u(w4.x); l4.x = f2bf_u(w4.x - bfu2f(h4.x));
  h4.y = f2bf_u(w4.y); l4.y = f2bf_u(w4.y - bfu2f(h4.y));
  h4.z = f2bf_u(w4.z); l4.z = f2bf_u(w4.z - bfu2f(h4.z));
  h4.w = f2bf_u(w4.w); l4.w = f2bf_u(w4.w - bfu2f(h4.w));
  *(ushort4*)&hi[off] = h4;
  *(ushort4*)&lo[off] = l4;
}

// ======== gx GEMM tile body (256-thread) ========
__device__ __forceinline__ void gx_tile(
    int tid, int m0, int yy,
    const float* __restrict__ X,
    const unsigned short* __restrict__ WhiF, const unsigned short* __restrict__ WloF,
    const unsigned short* __restrict__ WhiB, const unsigned short* __restrict__ WloB,
    const float* __restrict__ bf, const float* __restrict__ bb,
    unsigned short* __restrict__ bufF, unsigned short* __restrict__ bufB, int cF, int cB,
    unsigned short* Abf, unsigned short* Bhi, unsigned short* Blo)
{
  const unsigned short* Whi; const unsigned short* Wlo;
  const float* bias; unsigned short* buf; int c;
  if (yy < 6) { Whi = WhiF; Wlo = WloF; bias = bf; buf = bufF; c = cF; }
  else        { yy -= 6; Whi = WhiB; Wlo = WloB; bias = bb; buf = bufB; c = cB; }
  const int n0 = yy * 64;

  const int l  = tid & 63;
  const int w  = tid >> 6;
  const int fr = l & 15;
  const int fk = (l >> 4) * 8;

  float4v acc[2][4];
#pragma unroll
  for (int a = 0; a < 2; ++a)
#pragma unroll
    for (int nb = 0; nb < 4; ++nb) acc[a][nb] = (float4v)0.0f;

  for (int k0 = 0; k0 < DIN; k0 += 32) {
#pragma unroll
    for (int j = 0; j < 4; ++j) {
      int row = (tid >> 3) + j * 32;
      int kq  = (tid & 7) * 4;
      int r   = m0 + row;
      int b_  = r >> 6, tt = r & 63;
      int xrow = b_ * SEQL + c * TCH + tt;
      float4 x4 = *(const float4*)&X[(size_t)xrow * DIN + k0 + kq];
      ushort4 h4 = {f2bf_u(x4.x), f2bf_u(x4.y), f2bf_u(x4.z), f2bf_u(x4.w)};
      *(ushort4*)&Abf[row * 40 + kq] = h4;
    }
    {
      int half = tid & 1;
      int cc   = tid >> 1;
      int col  = cc >> 1;
      int seg  = (cc & 1) * 16;
      const unsigned short* srcw = (half ? Wlo : Whi) + (size_t)(n0 + col) * DIN + k0 + seg;
      unsigned short* dst = (half ? Blo : Bhi) + col * 40 + seg;
      *(short8v*)dst       = *(const short8v*)srcw;
      *(short8v*)(dst + 8) = *(const short8v*)(srcw + 8);
    }
    __syncthreads();

    short8v ah[2], bh[4], blv[4];
#pragma unroll
    for (int a = 0; a < 2; ++a)
      ah[a] = *(const short8v*)&Abf[(w * 32 + a * 16 + fr) * 40 + fk];
#pragma unroll
    for (int nb = 0; nb < 4; ++nb) {
      bh[nb]  = *(const short8v*)&Bhi[(nb * 16 + fr) * 40 + fk];
      blv[nb] = *(const short8v*)&Blo[(nb * 16 + fr) * 40 + fk];
    }
#pragma unroll
    for (int a = 0; a < 2; ++a)
#pragma unroll
      for (int nb = 0; nb < 4; ++nb) {
        acc[a][nb] = __builtin_amdgcn_mfma_f32_16x16x32_bf16(ah[a], bh[nb],  acc[a][nb], 0, 0, 0);
        acc[a][nb] = __builtin_amdgcn_mfma_f32_16x16x32_bf16(ah[a], blv[nb], acc[a][nb], 0, 0, 0);
      }
    __syncthreads();
  }

#pragma unroll
  for (int a = 0; a < 2; ++a)
#pragma unroll
    for (int nb = 0; nb < 4; ++nb) {
      int gate = n0 + nb * 16 + fr;
      float bv_ = bias[gate];
#pragma unroll
      for (int reg = 0; reg < 4; ++reg) {
        int r = m0 + w * 32 + a * 16 + (l >> 4) * 4 + reg;
        buf[(size_t)r * G3 + gate] = f2bf_u(acc[a][nb][reg] + bv_);
      }
    }
}

// ======== GRU scan: one step (compile-time parity P). SINGLE-term Whh (plain bf16).
// 12 MFMA/step, 3 independent chains of depth 4. ========
template<int P>
__device__ __forceinline__ void gru_step(
    unsigned short (*hsbuf)[NBS * HSPAD], int col, int rq, int hidx,
    const short8v (&Bh)[3][4], const float (&bias_)[3],
    const GxB& Gc, float (&hold)[4], const int (&len_)[4], int t,
    __hip_bfloat16* (&rp)[4], int drp)
{
  const unsigned short* rd = &hsbuf[P][col * HSPAD + rq * 8];
  short8v ah[4];
#pragma unroll
  for (int ks = 0; ks < 4; ++ks)
    ah[ks] = *(const short8v*)(rd + ks * 32);

  float4v a0 = (float4v){bias_[0] + bfu2f(Gc.v[0][0]), bias_[0] + bfu2f(Gc.v[0][1]),
                         bias_[0] + bfu2f(Gc.v[0][2]), bias_[0] + bfu2f(Gc.v[0][3])};
  float4v a1 = (float4v){bias_[1] + bfu2f(Gc.v[1][0]), bias_[1] + bfu2f(Gc.v[1][1]),
                         bias_[1] + bfu2f(Gc.v[1][2]), bias_[1] + bfu2f(Gc.v[1][3])};
  float4v a2 = (float4v){bias_[2], bias_[2], bias_[2], bias_[2]};
#pragma unroll
  for (int ks = 0; ks < 4; ++ks) {
    a0 = __builtin_amdgcn_mfma_f32_16x16x32_bf16(ah[ks], Bh[0][ks], a0, 0, 0, 0);
    a1 = __builtin_amdgcn_mfma_f32_16x16x32_bf16(ah[ks], Bh[1][ks], a1, 0, 0, 0);
    a2 = __builtin_amdgcn_mfma_f32_16x16x32_bf16(ah[ks], Bh[2][ks], a2, 0, 0, 0);
  }

  unsigned short* wr = &hsbuf[P ^ 1][rq * 4 * HSPAD + hidx];
  float hv4[4]; bool act4[4];
#pragma unroll
  for (int reg = 0; reg < 4; ++reg) {
    float gr = a0[reg], gz = a1[reg], gn = a2[reg];
    float xn = bfu2f(Gc.v[2][reg]);
    float r = 1.0f / (1.0f + __expf(-gr));
    float z = 1.0f / (1.0f + __expf(-gz));
    float e2 = __expf(-2.0f * (xn + r * gn));
    float cand = (1.0f - e2) / (1.0f + e2);
    float hv = cand + z * (hold[reg] - cand);
    bool act = (t < len_[reg]);
    hv = act ? hv : hold[reg];
    hold[reg] = hv;
    hv4[reg] = hv;
    act4[reg] = act;
  }
  uint32_t p01, p23;
  asm("v_cvt_pk_bf16_f32 %0, %1, %2" : "=v"(p01) : "v"(hv4[0]), "v"(hv4[1]));
  asm("v_cvt_pk_bf16_f32 %0, %1, %2" : "=v"(p23) : "v"(hv4[2]), "v"(hv4[3]));
  unsigned short b0 = (unsigned short)(p01 & 0xFFFFu);
  unsigned short b1 = (unsigned short)(p01 >> 16);
  unsigned short b2 = (unsigned short)(p23 & 0xFFFFu);
  unsigned short b3 = (unsigned short)(p23 >> 16);
  wr[0 * HSPAD] = b0;
  wr[1 * HSPAD] = b1;
  wr[2 * HSPAD] = b2;
  wr[3 * HSPAD] = b3;
  if (act4[0]) *(unsigned short*)rp[0] = b0;
  if (act4[1]) *(unsigned short*)rp[1] = b1;
  if (act4[2]) *(unsigned short*)rp[2] = b2;
  if (act4[3]) *(unsigned short*)rp[3] = b3;
  rp[0] += drp; rp[1] += drp; rp[2] += drp; rp[3] += drp;

  asm volatile("s_waitcnt lgkmcnt(0)" ::: "memory");
  __builtin_amdgcn_s_barrier();
  __builtin_amdgcn_sched_barrier(0);
}

// ======== GRU scan block body (512-thread) ========
__device__ __forceinline__ void scan_block(
    int sb, int tid,
    const int* __restrict__ seqlens,
    const float* __restrict__ Whh_f, const float* __restrict__ Whh_b,
    const float* __restrict__ bhh_f, const float* __restrict__ bhh_b,
    const unsigned short* __restrict__ bufF, const unsigned short* __restrict__ bufB,
    float* __restrict__ hstate, __hip_bfloat16* __restrict__ rnn, int ci,
    unsigned short (*hsbuf)[NBS * HSPAD])
{
  const int fwd = (sb < NGRPS) ? 1 : 0;
  const int grp = fwd ? sb : (sb - NGRPS);
  const int b0  = grp * NBS;
  const int w   = tid >> 6;
  const int l   = tid & 63;
  const int col = l & 15;
  const int rq  = l >> 4;
  const int hidx = w * 16 + col;
  const float* Whh = fwd ? Whh_f : Whh_b;
  const float* bhh = fwd ? bhh_f : bhh_b;
  const unsigned short* buf = fwd ? bufF : bufB;
  const int c = fwd ? ci : (NCH - 1 - ci);

  __builtin_amdgcn_s_setprio(1);

  // single-term Whh: plain bf16 rounding (12 MFMA/step)
  short8v Bh[3][4];
  float bias_[3];
#pragma unroll
  for (int j = 0; j < 3; ++j) {
    const int g = j * HID + hidx;
    bias_[j] = bhh[g];
#pragma unroll
    for (int ks = 0; ks < 4; ++ks) {
      const float* p = Whh + (size_t)g * HID + ks * 32 + rq * 8;
      float4 x0 = *(const float4*)p;
      float4 x1 = *(const float4*)(p + 4);
      float v[8] = {x0.x, x0.y, x0.z, x0.w, x1.x, x1.y, x1.z, x1.w};
      short8v hi8;
#pragma unroll
      for (int e = 0; e < 8; ++e) hi8[e] = (short)f2bf_u(v[e]);
      Bh[j][ks] = hi8;
    }
  }

  int len_[4];
#pragma unroll
  for (int reg = 0; reg < 4; ++reg) len_[reg] = seqlens[b0 + rq * 4 + reg];
  int gmax = 0;
  for (int nb = 0; nb < NBS; ++nb) gmax = max(gmax, seqlens[b0 + nb]);

  float* hst = hstate + ((size_t)((fwd ? 0 : 1) * NGRPS + grp)) * (NBS * HID);
  float hold[4];
#pragma unroll
  for (int reg = 0; reg < 4; ++reg) {
    int nb = rq * 4 + reg;
    hold[reg] = (ci == 0) ? 0.0f : hst[nb * HID + hidx];
    hsbuf[0][nb * HSPAD + hidx] = f2bf_u(hold[reg]);
  }
  __syncthreads();

  int nsteps = gmax - c * TCH;
  nsteps = (nsteps > TCH) ? TCH : nsteps;

  const int tcb  = c * TCH;
  const int dofs = fwd ? 0 : HID;

  if (nsteps == TCH) {
    // ---- fast path: 64 steps, unroll-2, RAW gx buffers ----
    const int tt0 = fwd ? 0 : (TCH - 1);
    const int dt  = fwd ? 1 : -1;
    const int dgp = fwd ? G3 : -G3;
    const int drp = fwd ? OUTD : -OUTD;

    const unsigned short* gp[4];
    __hip_bfloat16* rp[4];
#pragma unroll
    for (int reg = 0; reg < 4; ++reg) {
      gp[reg] = buf + (size_t)((b0 + rq * 4 + reg) * TCH + tt0) * G3 + hidx;
      rp[reg] = rnn + (size_t)((b0 + rq * 4 + reg) * SEQL + tcb + tt0) * OUTD + dofs + hidx;
    }

    GxB GA, GB;
    auto LOADGX = [&](GxB& G) {
#pragma unroll
      for (int reg = 0; reg < 4; ++reg) {
        G.v[0][reg] = gp[reg][0];
        G.v[1][reg] = gp[reg][HID];
        G.v[2][reg] = gp[reg][2 * HID];
        gp[reg] += dgp;
      }
    };
    LOADGX(GA);
    LOADGX(GB);

    int t = tcb + tt0;
#pragma unroll 1
    for (int it = 0; it < TCH / 2; ++it) {
      gru_step<0>(hsbuf, col, rq, hidx, Bh, bias_, GA, hold, len_, t, rp, drp);
      t += dt;
      LOADGX(GA);
      gru_step<1>(hsbuf, col, rq, hidx, Bh, bias_, GB, hold, len_, t, rp, drp);
      t += dt;
      LOADGX(GB);
    }
  } else if (nsteps > 0) {
    // ---- slow path: partial chunk (single-term) ----
    float gxc[3][4], gxn[3][4];
    {
      int tt0 = fwd ? 0 : (nsteps - 1);
#pragma unroll
      for (int j = 0; j < 3; ++j)
#pragma unroll
        for (int reg = 0; reg < 4; ++reg)
          gxc[j][reg] = bfu2f(buf[(size_t)((b0 + rq * 4 + reg) * TCH + tt0) * G3 + j * HID + hidx]);
    }

    int cur = 0;
    for (int ss = 0; ss < nsteps; ++ss) {
      const int tt = fwd ? ss : (nsteps - 1 - ss);
      const int t  = tcb + tt;

      short8v ah[4];
#pragma unroll
      for (int ks = 0; ks < 4; ++ks)
        ah[ks] = *(const short8v*)&hsbuf[cur][col * HSPAD + ks * 32 + rq * 8];

      {
        int ssn = (ss + 1 < nsteps) ? (ss + 1) : ss;
        int ttn = fwd ? ssn : (nsteps - 1 - ssn);
#pragma unroll
        for (int j = 0; j < 3; ++j)
#pragma unroll
          for (int reg = 0; reg < 4; ++reg)
            gxn[j][reg] = bfu2f(buf[(size_t)((b0 + rq * 4 + reg) * TCH + ttn) * G3 + j * HID + hidx]);
      }

      float4v acc[3];
#pragma unroll
      for (int j = 0; j < 3; ++j)
        acc[j] = (float4v){bias_[j], bias_[j], bias_[j], bias_[j]};
#pragma unroll
      for (int ks = 0; ks < 4; ++ks)
#pragma unroll
        for (int j = 0; j < 3; ++j)
          acc[j] = __builtin_amdgcn_mfma_f32_16x16x32_bf16(ah[ks], Bh[j][ks], acc[j], 0, 0, 0);

#pragma unroll
      for (int reg = 0; reg < 4; ++reg) {
        int nb = rq * 4 + reg;
        float gr = acc[0][reg] + gxc[0][reg];
        float gz = acc[1][reg] + gxc[1][reg];
        float gn = acc[2][reg];
        float xn = gxc[2][reg];
        float r = 1.0f / (1.0f + __expf(-gr));
        float z = 1.0f / (1.0f + __expf(-gz));
        float e2 = __expf(-2.0f * (xn + r * gn));
        float cand = (1.0f - e2) / (1.0f + e2);
        float hv = (1.0f - z) * cand + z * hold[reg];
        bool act = (t < len_[reg]);
        hv = act ? hv : hold[reg];
        hold[reg] = hv;
        hsbuf[cur ^ 1][nb * HSPAD + hidx] = f2bf_u(hv);
        if (act)
          rnn[(size_t)((b0 + nb) * SEQL + t) * OUTD + dofs + hidx] = __float2bfloat16(hv);
      }
      asm volatile("s_waitcnt lgkmcnt(0)" ::: "memory");
      __builtin_amdgcn_s_barrier();
      __builtin_amdgcn_sched_barrier(0);
      cur ^= 1;

#pragma unroll
      for (int j = 0; j < 3; ++j)
#pragma unroll
        for (int reg = 0; reg < 4; ++reg) gxc[j][reg] = gxn[j][reg];
    }
  }

  __builtin_amdgcn_s_setprio(0);

#pragma unroll
  for (int reg = 0; reg < 4; ++reg)
    hst[(rq * 4 + reg) * HID + hidx] = hold[reg];
}

// ======== mlp 64-row tile body (256-thread) ========
__device__ __forceinline__ void mlp64_tile(
    int tid, int m0, int nh,
    const __hip_bfloat16* __restrict__ rnn,
    const unsigned short* __restrict__ Whi, const unsigned short* __restrict__ Wlo,
    const float* __restrict__ bmlp, const float* __restrict__ ctx,
    float* __restrict__ scoresH,
    unsigned short* Abf, unsigned short* BhiS, unsigned short* BloS)
{
  const int l  = tid & 63;
  const int w  = tid >> 6;
  const int fr = l & 15;
  const int fk = (l >> 4) * 8;

  float bl_[8], cl_[8];
#pragma unroll
  for (int nt = 0; nt < 8; ++nt) {
    bl_[nt] = bmlp[nh * 128 + nt * 16 + fr];
    cl_[nt] = ctx[nh * 128 + nt * 16 + fr];
  }

  float4v acc[8];
#pragma unroll
  for (int nt = 0; nt < 8; ++nt) acc[nt] = (float4v)0.0f;

  for (int k0 = 0; k0 < OUTD; k0 += 32) {
    {
      int row = tid >> 2;
      int kq  = (tid & 3) * 8;
      *(short8v*)&Abf[row * 40 + kq] =
          *(const short8v*)((const short*)rnn + (size_t)(m0 + row) * OUTD + k0 + kq);
    }
#pragma unroll
    for (int j = 0; j < 2; ++j) {
      int cid  = tid * 2 + j;
      int half = cid >> 8;
      int cc   = cid & 255;
      int colx = cc >> 1;
      int seg  = (cc & 1) * 16;
      const unsigned short* srcw = (half ? Wlo : Whi) + (size_t)(nh * 128 + colx) * OUTD + k0 + seg;
      unsigned short* dst = (half ? BloS : BhiS) + colx * 40 + seg;
      *(short8v*)dst       = *(const short8v*)srcw;
      *(short8v*)(dst + 8) = *(const short8v*)(srcw + 8);
    }
    __syncthreads();

    short8v a = *(const short8v*)&Abf[(w * 16 + fr) * 40 + fk];
#pragma unroll
    for (int nt = 0; nt < 8; ++nt) {
      short8v bh = *(const short8v*)&BhiS[(nt * 16 + fr) * 40 + fk];
      short8v bv = *(const short8v*)&BloS[(nt * 16 + fr) * 40 + fk];
      acc[nt] = __builtin_amdgcn_mfma_f32_16x16x32_bf16(a, bh, acc[nt], 0, 0, 0);
      acc[nt] = __builtin_amdgcn_mfma_f32_16x16x32_bf16(a, bv, acc[nt], 0, 0, 0);
    }
    __syncthreads();
  }

  float p[4] = {0.f, 0.f, 0.f, 0.f};
#pragma unroll
  for (int nt = 0; nt < 8; ++nt) {
    float bv_ = bl_[nt], cv = cl_[nt];
#pragma unroll
    for (int reg = 0; reg < 4; ++reg)
      p[reg] += fast_tanh(acc[nt][reg] + bv_) * cv;
  }
#pragma unroll
  for (int off = 1; off < 16; off <<= 1)
#pragma unroll
    for (int reg = 0; reg < 4; ++reg) p[reg] += __shfl_xor(p[reg], off, 64);
  if (fr == 0) {
#pragma unroll
    for (int reg = 0; reg < 4; ++reg)
      scoresH[(size_t)nh * MTOT + m0 + w * 16 + (l >> 4) * 4 + reg] = p[reg];
  }
}

// ---- standalone gx kernel (prologue + fallback) ----
__global__ __launch_bounds__(256) void gx_kernel(
    const float* __restrict__ X,
    const unsigned short* __restrict__ WhiF, const unsigned short* __restrict__ WloF,
    const unsigned short* __restrict__ WhiB, const unsigned short* __restrict__ WloB,
    const float* __restrict__ bf, const float* __restrict__ bb,
    unsigned short* __restrict__ bufF, unsigned short* __restrict__ bufB, int cF, int cB)
{
  __shared__ unsigned short Abf[128 * 40];
  __shared__ unsigned short Bhi[64 * 40];
  __shared__ unsigned short Blo[64 * 40];
  gx_tile(threadIdx.x, blockIdx.x * 128, blockIdx.y, X, WhiF, WloF, WhiB, WloB,
          bf, bb, bufF, bufB, cF, cB, Abf, Bhi, Blo);
}

// ---- standalone scan kernel (fallback) ----
__global__ __launch_bounds__(512, 2) void scan_kernel(
    const int* __restrict__ seqlens,
    const float* __restrict__ Whh_f, const float* __restrict__ Whh_b,
    const float* __restrict__ bhh_f, const float* __restrict__ bhh_b,
    const unsigned short* __restrict__ bufF, const unsigned short* __restrict__ bufB,
    float* __restrict__ hstate, __hip_bfloat16* __restrict__ rnn, int ci)
{
  __shared__ unsigned short hsbuf[2][NBS * HSPAD];
  scan_block(blockIdx.x, threadIdx.x, seqlens, Whh_f, Whh_b, bhh_f, bhh_b,
             bufF, bufB, hstate, rnn, ci, hsbuf);
}

// ---- fused kernel: blocks 0..63 scan chunk ci; blocks 64.. gx chunk ci+1 ----
__global__ __launch_bounds__(512, 2) void fused_kernel(
    const int* __restrict__ seqlens,
    const float* __restrict__ Whh_f, const float* __restrict__ Whh_b,
    const float* __restrict__ bhh_f, const float* __restrict__ bhh_b,
    const float* __restrict__ X,
    const unsigned short* __restrict__ WhiF, const unsigned short* __restrict__ WloF,
    const unsigned short* __restrict__ WhiB, const unsigned short* __restrict__ WloB,
    const float* __restrict__ bf, const float* __restrict__ bb,
    const unsigned short* __restrict__ rdF, const unsigned short* __restrict__ rdB,
    unsigned short* __restrict__ wrF, unsigned short* __restrict__ wrB,
    float* __restrict__ hstate, __hip_bfloat16* __restrict__ rnn, int ci)
{
  __shared__ unsigned short hsbuf[2][NBS * HSPAD];
  __shared__ unsigned short AbfS[2][128 * 40];
  __shared__ unsigned short BhiS[2][64 * 40];
  __shared__ unsigned short BloS[2][64 * 40];

  if (blockIdx.x < 2 * NGRPS) {
    scan_block(blockIdx.x, threadIdx.x, seqlens, Whh_f, Whh_b, bhh_f, bhh_b,
               rdF, rdB, hstate, rnn, ci, hsbuf);
  } else {
    const int gb   = blockIdx.x - 2 * NGRPS;
    const int half = threadIdx.x >> 8;
    const int htid = threadIdx.x & 255;
    const int t0   = gb * 2 + half;
    const int m0   = (t0 & 255) * 128;
    const int yy   = t0 >> 8;
    gx_tile(htid, m0, yy, X, WhiF, WloF, WhiB, WloB, bf, bb,
            wrF, wrB, ci + 1, NCH - 2 - ci, AbfS[half], BhiS[half], BloS[half]);
  }
}

// ---- fused final: blocks 0..63 scan chunk NCH-1; blocks 64.. mlp tiles for t in [64,192) ----
union ShFinal {
  unsigned short hs[2][NBS * HSPAD];
  struct { unsigned short A[2][64 * 40]; unsigned short Bh[2][128 * 40]; unsigned short Bl[2][128 * 40]; } m;
};
__global__ __launch_bounds__(512, 2) void fused_final(
    const int* __restrict__ seqlens,
    const float* __restrict__ Whh_f, const float* __restrict__ Whh_b,
    const float* __restrict__ bhh_f, const float* __restrict__ bhh_b,
    const unsigned short* __restrict__ rdF, const unsigned short* __restrict__ rdB,
    float* __restrict__ hstate, __hip_bfloat16* __restrict__ rnn,
    const unsigned short* __restrict__ mhi, const unsigned short* __restrict__ mlo,
    const float* __restrict__ bmlp, const float* __restrict__ ctx,
    float* __restrict__ scoresH)
{
  __shared__ ShFinal sh;
  if (blockIdx.x < 2 * NGRPS) {
    scan_block(blockIdx.x, threadIdx.x, seqlens, Whh_f, Whh_b, bhh_f, bhh_b,
               rdF, rdB, hstate, rnn, NCH - 1, sh.hs);
  } else {
    const int gb   = blockIdx.x - 2 * NGRPS;
    const int half = threadIdx.x >> 8;
    const int htid = threadIdx.x & 255;
    const int body = gb * 2 + half;
    const int nh   = body & 1;
    const int tile = body >> 1;
    const int b    = tile >> 1;
    const int t0   = 64 + (tile & 1) * 64;
    const int m0   = b * SEQL + t0;
    mlp64_tile(htid, m0, nh, rnn, mhi, mlo, bmlp, ctx, scoresH,
               sh.m.A[half], sh.m.Bh[half], sh.m.Bl[half]);
  }
}

// ---- tail kernel: per-batch missing scores + masked softmax + pool ----
__global__ __launch_bounds__(256) void tail_kernel(
    const int* __restrict__ seqlens,
    const __hip_bfloat16* __restrict__ rnn,
    const unsigned short* __restrict__ Whi, const unsigned short* __restrict__ Wlo,
    const float* __restrict__ bmlp, const float* __restrict__ ctx,
    const float* __restrict__ scoresH,
    float* __restrict__ out)
{
  __shared__ unsigned short Abf[128 * 40];
  __shared__ unsigned short BhiS[128 * 40];
  __shared__ unsigned short BloS[128 * 40];
  __shared__ float sm[SEQL];
  __shared__ float red[8];

  const int tid = threadIdx.x;
  const int b   = blockIdx.x;
  const int len = seqlens[b];
  const int l   = tid & 63;
  const int w   = tid >> 6;
  const int fr  = l & 15;
  const int fk  = (l >> 4) * 8;

  float pfull[2][4] = {{0.f, 0.f, 0.f, 0.f}, {0.f, 0.f, 0.f, 0.f}};

  for (int nh = 0; nh < 2; ++nh) {
    float bl_[8], cl_[8];
#pragma unroll
    for (int nt = 0; nt < 8; ++nt) {
      bl_[nt] = bmlp[nh * 128 + nt * 16 + fr];
      cl_[nt] = ctx[nh * 128 + nt * 16 + fr];
    }

    float4v acc[2][8];
#pragma unroll
    for (int a = 0; a < 2; ++a)
#pragma unroll
      for (int nt = 0; nt < 8; ++nt) acc[a][nt] = (float4v)0.0f;

    for (int k0 = 0; k0 < OUTD; k0 += 32) {
      {
        int row = tid >> 1;
        int kq  = (tid & 1) * 16;
        int t   = (row < 64) ? row : (row + 128);
        const short* src = (const short*)rnn + (size_t)(b * SEQL + t) * OUTD + k0 + kq;
        *(short8v*)&Abf[row * 40 + kq]     = *(const short8v*)src;
        *(short8v*)&Abf[row * 40 + kq + 8] = *(const short8v*)(src + 8);
      }
#pragma unroll
      for (int j = 0; j < 2; ++j) {
        int cid  = tid * 2 + j;
        int half = cid >> 8;
        int cc   = cid & 255;
        int colx = cc >> 1;
        int seg  = (cc & 1) * 16;
        const unsigned short* srcw = (half ? Wlo : Whi) + (size_t)(nh * 128 + colx) * OUTD + k0 + seg;
        unsigned short* dst = (half ? BloS : BhiS) + colx * 40 + seg;
        *(short8v*)dst       = *(const short8v*)srcw;
        *(short8v*)(dst + 8) = *(const short8v*)(srcw + 8);
      }
      __syncthreads();

      short8v ah0 = *(const short8v*)&Abf[(w * 32 + fr) * 40 + fk];
      short8v ah1 = *(const short8v*)&Abf[(w * 32 + 16 + fr) * 40 + fk];
#pragma unroll
      for (int nt = 0; nt < 8; ++nt) {
        short8v bh = *(const short8v*)&BhiS[(nt * 16 + fr) * 40 + fk];
        short8v bv = *(const short8v*)&BloS[(nt * 16 + fr) * 40 + fk];
        acc[0][nt] = __builtin_amdgcn_mfma_f32_16x16x32_bf16(ah0, bh, acc[0][nt], 0, 0, 0);
        acc[0][nt] = __builtin_amdgcn_mfma_f32_16x16x32_bf16(ah0, bv, acc[0][nt], 0, 0, 0);
        acc[1][nt] = __builtin_amdgcn_mfma_f32_16x16x32_bf16(ah1, bh, acc[1][nt], 0, 0, 0);
        acc[1][nt] = __builtin_amdgcn_mfma_f32_16x16x32_bf16(ah1, bv, acc[1][nt], 0, 0, 0);
      }
      __syncthreads();
    }

#pragma unroll
    for (int a = 0; a < 2; ++a)
#pragma unroll
      for (int nt = 0; nt < 8; ++nt) {
        float bv_ = bl_[nt], cv = cl_[nt];
#pragma unroll
        for (int reg = 0; reg < 4; ++reg)
          pfull[a][reg] += fast_tanh(acc[a][nt][reg] + bv_) * cv;
      }
  }

#pragma unroll
  for (int a = 0; a < 2; ++a) {
#pragma unroll
    for (int off = 1; off < 16; off <<= 1)
#pragma unroll
      for (int reg = 0; reg < 4; ++reg) pfull[a][reg] += __shfl_xor(pfull[a][reg], off, 64);
  }
  if (fr == 0) {
#pragma unroll
    for (int a = 0; a < 2; ++a)
#pragma unroll
      for (int reg = 0; reg < 4; ++reg) {
        int rr = w * 32 + a * 16 + (l >> 4) * 4 + reg;
        int t  = (rr < 64) ? rr : (rr + 128);
        sm[t] = pfull[a][reg];
      }
  }
  if (tid < 128)
    sm[64 + tid] = scoresH[b * SEQL + 64 + tid] + scoresH[(size_t)MTOT + b * SEQL + 64 + tid];
  __syncthreads();

  float s = (tid < len) ? sm[tid] : -3.4e38f;
  float wm = s;
#pragma unroll
  for (int off = 32; off > 0; off >>= 1) wm = fmaxf(wm, __shfl_xor(wm, off, 64));
  if ((tid & 63) == 0) red[tid >> 6] = wm;
  __syncthreads();
  float bm = fmaxf(fmaxf(red[0], red[1]), fmaxf(red[2], red[3]));

  float e = (tid < len) ? __expf(s - bm) : 0.0f;
  __syncthreads();
  sm[tid] = e;
  float sum = e;
#pragma unroll
  for (int off = 32; off > 0; off >>= 1) sum += __shfl_xor(sum, off, 64);
  if ((tid & 63) == 0) red[4 + (tid >> 6)] = sum;
  __syncthreads();
  float inv = 1.0f / (red[4] + red[5] + red[6] + red[7]);

  float acc = 0.0f;
  for (int l2 = 0; l2 < len; ++l2)
    acc += sm[l2] * __bfloat162float(rnn[(size_t)(b * SEQL + l2) * OUTD + tid]);
  out[b * OUTD + tid] = acc * inv;
}

// ---- K3 full (fallback path) ----
__global__ __launch_bounds__(256) void mlp_score(
    const __hip_bfloat16* __restrict__ rnn,
    const unsigned short* __restrict__ Whi, const unsigned short* __restrict__ Wlo,
    const float* __restrict__ bmlp, const float* __restrict__ ctx,
    float* __restrict__ scoresH)
{
  __shared__ unsigned short Abf[128 * 40];
  __shared__ unsigned short BhiS[128 * 40];
  __shared__ unsigned short BloS[128 * 40];

  const int tid = threadIdx.x;
  const int m0  = blockIdx.x * 128;
  const int nh  = blockIdx.y;
  const int l   = tid & 63;
  const int w   = tid >> 6;
  const int fr  = l & 15;
  const int fk  = (l >> 4) * 8;

  float bl_[8], cl_[8];
#pragma unroll
  for (int nt = 0; nt < 8; ++nt) {
    bl_[nt] = bmlp[nh * 128 + nt * 16 + fr];
    cl_[nt] = ctx[nh * 128 + nt * 16 + fr];
  }

  float4v acc[2][8];
#pragma unroll
  for (int a = 0; a < 2; ++a)
#pragma unroll
    for (int nt = 0; nt < 8; ++nt) acc[a][nt] = (float4v)0.0f;

  for (int k0 = 0; k0 < OUTD; k0 += 32) {
    {
      int row = tid >> 1;
      int kq  = (tid & 1) * 16;
      const short* src = (const short*)rnn + (size_t)(m0 + row) * OUTD + k0 + kq;
      *(short8v*)&Abf[row * 40 + kq]     = *(const short8v*)src;
      *(short8v*)&Abf[row * 40 + kq + 8] = *(const short8v*)(src + 8);
    }
#pragma unroll
    for (int j = 0; j < 2; ++j) {
      int cid  = tid * 2 + j;
      int half = cid >> 8;
      int cc   = cid & 255;
      int colx = cc >> 1;
      int seg  = (cc & 1) * 16;
      const unsigned short* srcw = (half ? Wlo : Whi) + (size_t)(nh * 128 + colx) * OUTD + k0 + seg;
      unsigned short* dst = (half ? BloS : BhiS) + colx * 40 + seg;
      *(short8v*)dst       = *(const short8v*)srcw;
      *(short8v*)(dst + 8) = *(const short8v*)(srcw + 8);
    }
    __syncthreads();

    short8v ah0 = *(const short8v*)&Abf[(w * 32 + fr) * 40 + fk];
    short8v ah1 = *(const short8v*)&Abf[(w * 32 + 16 + fr) * 40 + fk];
#pragma unroll
    for (int nt = 0; nt < 8; ++nt) {
      short8v bh = *(const short8v*)&BhiS[(nt * 16 + fr) * 40 + fk];
      short8v bv = *(const short8v*)&BloS[(nt * 16 + fr) * 40 + fk];
      acc[0][nt] = __builtin_amdgcn_mfma_f32_16x16x32_bf16(ah0, bh, acc[0][nt], 0, 0, 0);
      acc[0][nt] = __builtin_amdgcn_mfma_f32_16x16x32_bf16(ah0, bv, acc[0][nt], 0, 0, 0);
      acc[1][nt] = __builtin_amdgcn_mfma_f32_16x16x32_bf16(ah1, bh, acc[1][nt], 0, 0, 0);
      acc[1][nt] = __builtin_amdgcn_mfma_f32_16x16x32_bf16(ah1, bv, acc[1][nt], 0, 0, 0);
    }
    __syncthreads();
  }

#pragma unroll
  for (int a = 0; a < 2; ++a) {
    float p[4] = {0.f, 0.f, 0.f, 0.f};
#pragma unroll
    for (int nt = 0; nt < 8; ++nt) {
      float bv_ = bl_[nt], cv = cl_[nt];
#pragma unroll
      for (int reg = 0; reg < 4; ++reg)
        p[reg] += fast_tanh(acc[a][nt][reg] + bv_) * cv;
    }
#pragma unroll
    for (int off = 1; off < 16; off <<= 1)
#pragma unroll
      for (int reg = 0; reg < 4; ++reg) p[reg] += __shfl_xor(p[reg], off, 64);
    if (fr == 0) {
#pragma unroll
      for (int reg = 0; reg < 4; ++reg)
        scoresH[(size_t)nh * MTOT + m0 + w * 32 + a * 16 + (l >> 4) * 4 + reg] = p[reg];
    }
  }
}

// ---- K4: masked softmax over l + weighted pool (fallback path) ----
__global__ __launch_bounds__(256) void softmax_pool(
    const int* __restrict__ seqlens,
    const float* __restrict__ scoresH,
    const __hip_bfloat16* __restrict__ rnn,
    float* __restrict__ out)
{
  const int b = blockIdx.x;
  const int len = seqlens[b];
  const int tid = threadIdx.x;
  __shared__ float sm[SEQL];
  __shared__ float red[8];

  float s = (tid < len)
      ? (scoresH[b * SEQL + tid] + scoresH[(size_t)MTOT + b * SEQL + tid])
      : -3.4e38f;
  float wm = s;
#pragma unroll
  for (int off = 32; off > 0; off >>= 1) wm = fmaxf(wm, __shfl_xor(wm, off, 64));
  if ((tid & 63) == 0) red[tid >> 6] = wm;
  __syncthreads();
  float bm = fmaxf(fmaxf(red[0], red[1]), fmaxf(red[2], red[3]));

  float e = (tid < len) ? expf(s - bm) : 0.0f;
  sm[tid] = e;
  float sum = e;
#pragma unroll
  for (int off = 32; off > 0; off >>= 1) sum += __shfl_xor(sum, off, 64);
  if ((tid & 63) == 0) red[4 + (tid >> 6)] = sum;
  __syncthreads();
  float inv = 1.0f / (red[4] + red[5] + red[6] + red[7]);

  float acc = 0.0f;
  for (int l = 0; l < len; ++l)
    acc += sm[l] * __bfloat162float(rnn[(size_t)(b * SEQL + l) * OUTD + tid]);
  out[b * OUTD + tid] = acc * inv;
}

extern "C" void kernel_launch(void* const* d_in, const int* in_sizes, int n_in,
                              void* d_out, int out_size, void* d_ws, size_t ws_size,
                              hipStream_t stream) {
  const float* seq    = (const float*)d_in[0];
  const int*   lens   = (const int*)d_in[1];
  const float* Wih_f  = (const float*)d_in[2];
  const float* Whh_f  = (const float*)d_in[3];
  const float* bih_f  = (const float*)d_in[4];
  const float* bhh_f  = (const float*)d_in[5];
  const float* Wih_b  = (const float*)d_in[6];
  const float* Whh_b  = (const float*)d_in[7];
  const float* bih_b  = (const float*)d_in[8];
  const float* bhh_b  = (const float*)d_in[9];
  const float* Wmlp   = (const float*)d_in[10];
  const float* bmlp   = (const float*)d_in[11];
  const float* ctx    = (const float*)d_in[12];
  float* out = (float*)d_out;

  const size_t BUFSZ = (size_t)MCH * G3;
  const size_t needOverlap =
      4 * BUFSZ * 2 + (size_t)MTOT * OUTD * 2 + 2 * (size_t)MTOT * 4 +
      2 * BATCH * HID * 4 + 2 * (size_t)OUTD * OUTD * 2 + 4 * (size_t)G3 * DIN * 2;
  const bool overlap = (ws_size >= needOverlap);

  unsigned short* buf0F = (unsigned short*)d_ws;
  unsigned short* buf0B = buf0F + BUFSZ;
  unsigned short* buf1F = overlap ? (buf0B + BUFSZ) : buf0F;
  unsigned short* buf1B = overlap ? (buf1F + BUFSZ) : buf0B;
  unsigned short* tail  = overlap ? (buf1B + BUFSZ) : (buf0B + BUFSZ);

  __hip_bfloat16* rnn  = (__hip_bfloat16*)tail;
  float* scoresH = (float*)((unsigned short*)rnn + (size_t)MTOT * OUTD);
  float* hstate  = scoresH + 2 * (size_t)MTOT;
  unsigned short* mhi = (unsigned short*)(hstate + 2 * BATCH * HID);
  unsigned short* mlo = mhi + OUTD * OUTD;
  unsigned short* fhi = mlo + OUTD * OUTD;
  unsigned short* flo = fhi + G3 * DIN;
  unsigned short* bhi2 = flo + G3 * DIN;
  unsigned short* blo2 = bhi2 + G3 * DIN;

  prep_split<<<dim3(256), 256, 0, stream>>>(Wmlp, mhi, mlo, Wih_f, fhi, flo, Wih_b, bhi2, blo2);

  if (overlap) {
    unsigned short* bp[2][2] = {{buf0F, buf0B}, {buf1F, buf1B}};
    gx_kernel<<<dim3(256, 12), 256, 0, stream>>>(seq, fhi, flo, bhi2, blo2, bih_f, bih_b,
                                                 bp[0][0], bp[0][1], 0, NCH - 1);
    for (int k = 0; k < NCH - 1; ++k) {
      fused_kernel<<<dim3(2 * NGRPS + NGXT / 2), 512, 0, stream>>>(
          lens, Whh_f, Whh_b, bhh_f, bhh_b,
          seq, fhi, flo, bhi2, blo2, bih_f, bih_b,
          bp[k & 1][0], bp[k & 1][1], bp[(k + 1) & 1][0], bp[(k + 1) & 1][1],
          hstate, rnn, k);
    }
    fused_final<<<dim3(2 * NGRPS + 1024), 512, 0, stream>>>(
        lens, Whh_f, Whh_b, bhh_f, bhh_b,
        bp[(NCH - 1) & 1][0], bp[(NCH - 1) & 1][1], hstate, rnn,
        mhi, mlo, bmlp, ctx, scoresH);
    tail_kernel<<<dim3(BATCH), 256, 0, stream>>>(lens, rnn, mhi, mlo, bmlp, ctx, scoresH, out);
  } else {
    for (int ci = 0; ci < NCH; ++ci) {
      gx_kernel<<<dim3(256, 12), 256, 0, stream>>>(seq, fhi, flo, bhi2, blo2, bih_f, bih_b,
                                                   buf0F, buf0B, ci, NCH - 1 - ci);
      scan_kernel<<<dim3(2 * NGRPS), 512, 0, stream>>>(
          lens, Whh_f, Whh_b, bhh_f, bhh_b, buf0F, buf0B, hstate, rnn, ci);
    }
    mlp_score<<<dim3(MTOT / 128, 2), 256, 0, stream>>>(rnn, mhi, mlo, bmlp, ctx, scoresH);
    softmax_pool<<<dim3(BATCH), 256, 0, stream>>>(lens, scoresH, rnn, out);
  }
}